// Round 3
// baseline (461.408 us; speedup 1.0000x reference)
//
#include <hip/hip_runtime.h>
#include <math.h>

#define DIMN 1024
#define NH 16
#define HD 64
#define BATCH 2
#define SEQ 2048
#define MROWS (BATCH*SEQ)   // 4096

typedef unsigned short u16;
typedef unsigned int u32;
typedef __attribute__((ext_vector_type(8))) short bf16x8;  // 8 bf16 = 4 VGPR
typedef __attribute__((ext_vector_type(4))) float f32x4;

__device__ __forceinline__ u16 f2bf(float f) {             // RNE float->bf16 (bits)
    unsigned u = __float_as_uint(f);
    u += 0x7FFF + ((u >> 16) & 1);
    return (u16)(u >> 16);
}
__device__ __forceinline__ float bf2f(u16 s) {
    return __uint_as_float(((unsigned)s) << 16);
}

#define GLOADLDS16(g, s)                                                     \
    __builtin_amdgcn_global_load_lds(                                        \
        (const __attribute__((address_space(1))) void*)(g),                  \
        (__attribute__((address_space(3))) void*)(s), 16, 0, 0)

// ---------------- hi/lo split: fp32 -> bf16 hi + bf16 lo ----------------
__global__ __launch_bounds__(256)
void split_hilo(const float* __restrict__ src, u16* __restrict__ h,
                u16* __restrict__ l, int n4)
{
    int i = blockIdx.x * 256 + threadIdx.x;
    if (i >= n4) return;
    float4 v = ((const float4*)src)[i];
    ushort4 hv, lv;
    hv.x = f2bf(v.x); lv.x = f2bf(v.x - bf2f(hv.x));
    hv.y = f2bf(v.y); lv.y = f2bf(v.y - bf2f(hv.y));
    hv.z = f2bf(v.z); lv.z = f2bf(v.z - bf2f(hv.z));
    hv.w = f2bf(v.w); lv.w = f2bf(v.w - bf2f(hv.w));
    ((ushort4*)h)[i] = hv;
    ((ushort4*)l)[i] = lv;
}

// ---------------- split-bf16 MFMA GEMM: Y = A @ W^T + bias ----------------
// 128x128 tile, BK=32, 4 waves (2x2), 64x64/wave = 4x4 16x16x32 frags.
// 3 MFMA per frag pair: hi*hi + hi*lo + lo*hi (fp32-grade).
// QKV epilogue: z=0 -> Q hi/lo (scaled 1/32, [B,H,T,64]);
//               z=1 -> K hi/lo (d-swizzled d^((t&7)<<3));  z=2 -> V fp32.
#define BM 128
#define BN 128
#define BK 32

template<bool QKV>
__global__ __launch_bounds__(256)
void mfma_gemm(const u16* __restrict__ Ah, const u16* __restrict__ Al,
               const u16* __restrict__ Wh0, const u16* __restrict__ Wl0,
               const u16* __restrict__ Wh1, const u16* __restrict__ Wl1,
               const u16* __restrict__ Wh2, const u16* __restrict__ Wl2,
               const float* __restrict__ b0, const float* __restrict__ b1,
               const float* __restrict__ b2,
               u16* __restrict__ Qh, u16* __restrict__ Ql,
               u16* __restrict__ Kh, u16* __restrict__ Kl,
               float* __restrict__ Vw, float* __restrict__ Yout)
{
    __shared__ u16 AhS[BM*BK], AlS[BM*BK], WhS[BN*BK], WlS[BN*BK];  // 32 KB

    const u16* Wh = Wh0; const u16* Wl = Wl0; const float* bias = b0;
    if (QKV) {
        if (blockIdx.z == 1)      { Wh = Wh1; Wl = Wl1; bias = b1; }
        else if (blockIdx.z == 2) { Wh = Wh2; Wl = Wl2; bias = b2; }
    }

    const int tid  = threadIdx.x;
    const int lane = tid & 63;
    const int wid  = tid >> 6;
    const int wr   = wid >> 1;
    const int wc   = wid & 1;

    const int m0 = blockIdx.y * BM;
    const int n0 = blockIdx.x * BN;

    const int srow = lane >> 2;
    const int skc  = (lane & 3) << 3;
    const int c0 = wid * 2, c1 = wid * 2 + 1;
    const size_t aoffg0 = (size_t)(m0 + c0*16 + srow) * DIMN + skc;
    const size_t aoffg1 = (size_t)(m0 + c1*16 + srow) * DIMN + skc;
    const size_t woffg0 = (size_t)(n0 + c0*16 + srow) * DIMN + skc;
    const size_t woffg1 = (size_t)(n0 + c1*16 + srow) * DIMN + skc;

    f32x4 acc[4][4];
    #pragma unroll
    for (int m = 0; m < 4; ++m)
        #pragma unroll
        for (int n = 0; n < 4; ++n)
            acc[m][n] = (f32x4){0.f, 0.f, 0.f, 0.f};

    const int fr = lane & 15;
    const int fq = lane >> 4;
    const int aoff = (wr*64 + fr) * BK + fq*8;
    const int boff = (wc*64 + fr) * BK + fq*8;

    for (int k0 = 0; k0 < DIMN; k0 += BK) {
        GLOADLDS16(Ah + aoffg0 + k0, &AhS[c0*512]);
        GLOADLDS16(Ah + aoffg1 + k0, &AhS[c1*512]);
        GLOADLDS16(Al + aoffg0 + k0, &AlS[c0*512]);
        GLOADLDS16(Al + aoffg1 + k0, &AlS[c1*512]);
        GLOADLDS16(Wh + woffg0 + k0, &WhS[c0*512]);
        GLOADLDS16(Wh + woffg1 + k0, &WhS[c1*512]);
        GLOADLDS16(Wl + woffg0 + k0, &WlS[c0*512]);
        GLOADLDS16(Wl + woffg1 + k0, &WlS[c1*512]);
        __syncthreads();

        bf16x8 ah[4], al[4], bh[4], bl[4];
        #pragma unroll
        for (int m = 0; m < 4; ++m) {
            ah[m] = *(const bf16x8*)&AhS[aoff + m*16*BK];
            al[m] = *(const bf16x8*)&AlS[aoff + m*16*BK];
        }
        #pragma unroll
        for (int n = 0; n < 4; ++n) {
            bh[n] = *(const bf16x8*)&WhS[boff + n*16*BK];
            bl[n] = *(const bf16x8*)&WlS[boff + n*16*BK];
        }
        #pragma unroll
        for (int m = 0; m < 4; ++m)
            #pragma unroll
            for (int n = 0; n < 4; ++n) {
                acc[m][n] = __builtin_amdgcn_mfma_f32_16x16x32_bf16(ah[m], bh[n], acc[m][n], 0, 0, 0);
                acc[m][n] = __builtin_amdgcn_mfma_f32_16x16x32_bf16(ah[m], bl[n], acc[m][n], 0, 0, 0);
                acc[m][n] = __builtin_amdgcn_mfma_f32_16x16x32_bf16(al[m], bh[n], acc[m][n], 0, 0, 0);
            }
        __syncthreads();
    }

    // C/D map: col = lane&15, row = (lane>>4)*4 + j   [m89-verified]
    #pragma unroll
    for (int n = 0; n < 4; ++n) {
        const int col = n0 + wc*64 + n*16 + fr;
        const float bv = bias[col];
        #pragma unroll
        for (int m = 0; m < 4; ++m) {
            #pragma unroll
            for (int j = 0; j < 4; ++j) {
                const int row = m0 + wr*64 + m*16 + fq*4 + j;
                float v = acc[m][n][j] + bv;
                if (QKV) {
                    const int b_ = row >> 11, t = row & (SEQ - 1);
                    const int hh = col >> 6, d = col & 63;
                    const size_t rb = (((size_t)b_*NH + hh)*SEQ + t)*HD;
                    if (blockIdx.z == 0) {            // Q: scaled, plain
                        v *= 0.03125f;
                        u16 hv = f2bf(v), lv = f2bf(v - bf2f(hv));
                        Qh[rb + d] = hv; Ql[rb + d] = lv;
                    } else if (blockIdx.z == 1) {     // K: swizzled
                        u16 hv = f2bf(v), lv = f2bf(v - bf2f(hv));
                        const int ds = d ^ ((t & 7) << 3);
                        Kh[rb + ds] = hv; Kl[rb + ds] = lv;
                    } else {                          // V: fp32 plain
                        Vw[rb + d] = v;
                    }
                } else {
                    Yout[(size_t)row*DIMN + col] = v;
                }
            }
        }
    }
}

// ---------------- V transpose + hi/lo: [B,H,T,64] fp32 -> [B,H,64,T] bf16 hi/lo ----
__global__ __launch_bounds__(256)
void convV(const float* __restrict__ Vw, u16* __restrict__ Vth, u16* __restrict__ Vtl)
{
    __shared__ float Vs[64][68];
    const int tid = threadIdx.x;
    const int bh = blockIdx.y;
    const int t0 = blockIdx.x * 64;
    const float* src = Vw + ((size_t)bh*SEQ + t0)*HD;
    #pragma unroll
    for (int k = 0; k < 4; ++k) {
        int f4 = tid + k*256;
        int r = f4 >> 4, c4 = (f4 & 15) << 2;
        *(float4*)&Vs[r][c4] = *(const float4*)(src + (size_t)r*HD + c4);
    }
    __syncthreads();
    const int d  = tid >> 2;
    const int ts = (tid & 3) << 4;
    u16* oh = Vth + ((size_t)bh*HD + d)*SEQ + t0 + ts;
    u16* ol = Vtl + ((size_t)bh*HD + d)*SEQ + t0 + ts;
    #pragma unroll
    for (int p = 0; p < 4; ++p) {
        ushort4 hv, lv; float v;
        v = Vs[ts + p*4 + 0][d]; hv.x = f2bf(v); lv.x = f2bf(v - bf2f(hv.x));
        v = Vs[ts + p*4 + 1][d]; hv.y = f2bf(v); lv.y = f2bf(v - bf2f(hv.y));
        v = Vs[ts + p*4 + 2][d]; hv.z = f2bf(v); lv.z = f2bf(v - bf2f(hv.z));
        v = Vs[ts + p*4 + 3][d]; hv.w = f2bf(v); lv.w = f2bf(v - bf2f(hv.w));
        *(ushort4*)(oh + p*4) = hv;
        *(ushort4*)(ol + p*4) = lv;
    }
}

// ---------------- MFMA flash attention ----------------
// QB=64 (4 waves x 16 q-rows), KB=32. Swapped QK^T: S^T = mfma(K, Q) so each
// lane holds 8 scores of one q-row (q = lane&15) -> in-register softmax.
// PV: O^T = mfma(Vt, P); P round-trips per-wave-private LDS (no barrier).
// K LDS tile is global-pre-swizzled (conflict-free); Vt/P naturally free.
// Double-buffered K/V staging via global_load_lds: ONE barrier per tile.
__global__ __launch_bounds__(256)
void attn_mfma(const u16* __restrict__ Qhg, const u16* __restrict__ Qlg,
               const u16* __restrict__ Khg, const u16* __restrict__ Klg,
               const u16* __restrict__ Vthg, const u16* __restrict__ Vtlg,
               u16* __restrict__ AH, u16* __restrict__ AL)
{
    __shared__ u16 KVS[2][4][2048];   // [buf][Kh,Kl,Vth,Vtl][tile] 32 KB
    __shared__ u16 PhS[4][512];       // per-wave P hi [16q][32kc] 2 KB
    __shared__ u16 PlS[4][512];       // 2 KB

    const int tid  = threadIdx.x;
    const int lane = tid & 63;
    const int w    = tid >> 6;
    const int fr   = lane & 15;
    const int fq   = lane >> 4;
    const int qt   = blockIdx.x;
    const int bh   = blockIdx.y;
    const int b_   = bh >> 4;
    const int h    = bh & 15;

    const int qabs = qt*64 + w*16 + fr;   // this lane's q row (token)
    const int nt   = 2*qt + 2;            // k-tiles to process

    // Q fragments (B-operand): tile-invariant, straight from global.
    bf16x8 qh[2], ql[2];
    {
        const size_t qrow = ((size_t)bh*SEQ + qabs)*HD;
        #pragma unroll
        for (int ks = 0; ks < 2; ++ks) {
            qh[ks] = *(const bf16x8*)&Qhg[qrow + ks*32 + (fq<<3)];
            ql[ks] = *(const bf16x8*)&Qlg[qrow + ks*32 + (fq<<3)];
        }
    }

    auto stage = [&](int buf, int kt2) {
        u16* dst = &KVS[buf][w][0];
        if (w < 2) {
            const u16* g = (w == 0 ? Khg : Klg) +
                ((size_t)bh*SEQ + (size_t)kt2*32 + (lane>>3))*HD + ((lane&7)<<3);
            #pragma unroll
            for (int i = 0; i < 4; ++i)
                GLOADLDS16(g + (size_t)i*8*HD, dst + i*512);
        } else {
            const u16* g = (w == 2 ? Vthg : Vtlg) +
                ((size_t)bh*HD + (lane>>2))*SEQ + (size_t)kt2*32 + ((lane&3)<<3);
            #pragma unroll
            for (int i = 0; i < 4; ++i)
                GLOADLDS16(g + (size_t)i*16*SEQ, dst + i*512);
        }
    };

    f32x4 o[4];
    #pragma unroll
    for (int md = 0; md < 4; ++md) o[md] = (f32x4){0.f,0.f,0.f,0.f};
    float mrun = -INFINITY, lrun = 0.f;

    stage(0, 0);
    int cur = 0;

    for (int kt = 0; kt < nt; ++kt) {
        __syncthreads();                       // staged tile landed (vmcnt drains)
        if (kt + 1 < nt) stage(cur ^ 1, kt + 1);

        // ---- QK^T (S^T): A = K tile (rows kc), B = Q frags ----
        f32x4 s0 = (f32x4){0.f,0.f,0.f,0.f};
        f32x4 s1 = (f32x4){0.f,0.f,0.f,0.f};
        #pragma unroll
        for (int ks = 0; ks < 2; ++ks) {
            const int sl = (((ks*4 + fq) ^ (fr & 7)) << 3);   // swizzled d-slot
            bf16x8 a0h = *(const bf16x8*)&KVS[cur][0][fr*64 + sl];
            bf16x8 a0l = *(const bf16x8*)&KVS[cur][1][fr*64 + sl];
            bf16x8 a1h = *(const bf16x8*)&KVS[cur][0][(16+fr)*64 + sl];
            bf16x8 a1l = *(const bf16x8*)&KVS[cur][1][(16+fr)*64 + sl];
            s0 = __builtin_amdgcn_mfma_f32_16x16x32_bf16(a0h, qh[ks], s0, 0,0,0);
            s0 = __builtin_amdgcn_mfma_f32_16x16x32_bf16(a0h, ql[ks], s0, 0,0,0);
            s0 = __builtin_amdgcn_mfma_f32_16x16x32_bf16(a0l, qh[ks], s0, 0,0,0);
            s1 = __builtin_amdgcn_mfma_f32_16x16x32_bf16(a1h, qh[ks], s1, 0,0,0);
            s1 = __builtin_amdgcn_mfma_f32_16x16x32_bf16(a1h, ql[ks], s1, 0,0,0);
            s1 = __builtin_amdgcn_mfma_f32_16x16x32_bf16(a1l, qh[ks], s1, 0,0,0);
        }

        // causal mask: lane reg j holds kc = kt*32 + {m*16} + fq*4 + j for q=qabs
        const int kb = kt*32 + fq*4;
        #pragma unroll
        for (int j = 0; j < 4; ++j) {
            if (kb + j      > qabs) s0[j] = -INFINITY;
            if (kb + 16 + j > qabs) s1[j] = -INFINITY;
        }

        // ---- online softmax (row = q = fr, spread over fq lanes) ----
        float pm = fmaxf(fmaxf(fmaxf(s0[0],s0[1]), fmaxf(s0[2],s0[3])),
                         fmaxf(fmaxf(s1[0],s1[1]), fmaxf(s1[2],s1[3])));
        pm = fmaxf(pm, __shfl_xor(pm, 16));
        pm = fmaxf(pm, __shfl_xor(pm, 32));
        const float mnew = fmaxf(mrun, pm);
        const float fac  = __expf(mrun - mnew);
        float p[8];
        #pragma unroll
        for (int j = 0; j < 4; ++j) {
            p[j]   = __expf(s0[j] - mnew);
            p[4+j] = __expf(s1[j] - mnew);
        }
        float ls = ((p[0]+p[1]) + (p[2]+p[3])) + ((p[4]+p[5]) + (p[6]+p[7]));
        ls += __shfl_xor(ls, 16);
        ls += __shfl_xor(ls, 32);
        lrun = lrun * fac + ls;
        mrun = mnew;
        #pragma unroll
        for (int md = 0; md < 4; ++md) {
            o[md][0] *= fac; o[md][1] *= fac; o[md][2] *= fac; o[md][3] *= fac;
        }

        // ---- P -> bf16 hi/lo -> per-wave LDS [16q][32kc] ----
        u16 ph[8], pl[8];
        #pragma unroll
        for (int i = 0; i < 8; ++i) {
            ph[i] = f2bf(p[i]);
            pl[i] = f2bf(p[i] - bf2f(ph[i]));
        }
        {
            const int pb = fr*32 + fq*4;      // u16 index; m=1 adds +16
            *(u32*)&PhS[w][pb]      = (u32)ph[0] | ((u32)ph[1] << 16);
            *(u32*)&PhS[w][pb + 2]  = (u32)ph[2] | ((u32)ph[3] << 16);
            *(u32*)&PhS[w][pb + 16] = (u32)ph[4] | ((u32)ph[5] << 16);
            *(u32*)&PhS[w][pb + 18] = (u32)ph[6] | ((u32)ph[7] << 16);
            *(u32*)&PlS[w][pb]      = (u32)pl[0] | ((u32)pl[1] << 16);
            *(u32*)&PlS[w][pb + 2]  = (u32)pl[2] | ((u32)pl[3] << 16);
            *(u32*)&PlS[w][pb + 16] = (u32)pl[4] | ((u32)pl[5] << 16);
            *(u32*)&PlS[w][pb + 18] = (u32)pl[6] | ((u32)pl[7] << 16);
        }

        // ---- PV (O^T): A = Vt tile (rows d), B = P frags (same-wave LDS) ----
        bf16x8 bph = *(const bf16x8*)&PhS[w][fr*32 + (fq<<3)];
        bf16x8 bpl = *(const bf16x8*)&PlS[w][fr*32 + (fq<<3)];
        #pragma unroll
        for (int md = 0; md < 4; ++md) {
            bf16x8 avh = *(const bf16x8*)&KVS[cur][2][(md*16+fr)*32 + (fq<<3)];
            bf16x8 avl = *(const bf16x8*)&KVS[cur][3][(md*16+fr)*32 + (fq<<3)];
            o[md] = __builtin_amdgcn_mfma_f32_16x16x32_bf16(avh, bph, o[md], 0,0,0);
            o[md] = __builtin_amdgcn_mfma_f32_16x16x32_bf16(avh, bpl, o[md], 0,0,0);
            o[md] = __builtin_amdgcn_mfma_f32_16x16x32_bf16(avl, bph, o[md], 0,0,0);
        }
        cur ^= 1;
    }

    // ---- epilogue: O^T lane holds q=qabs, d = md*16 + fq*4 + j ----
    const float inv = 1.f / lrun;
    const size_t ob = ((size_t)b_*SEQ + qabs)*DIMN + h*64;
    #pragma unroll
    for (int md = 0; md < 4; ++md) {
        #pragma unroll
        for (int pr = 0; pr < 2; ++pr) {
            const int d0 = md*16 + fq*4 + pr*2;
            const float v0 = o[md][pr*2]   * inv;
            const float v1 = o[md][pr*2+1] * inv;
            u16 h0 = f2bf(v0), l0 = f2bf(v0 - bf2f(h0));
            u16 h1 = f2bf(v1), l1 = f2bf(v1 - bf2f(h1));
            *(u32*)&AH[ob + d0] = (u32)h0 | ((u32)h1 << 16);
            *(u32*)&AL[ob + d0] = (u32)l0 | ((u32)l1 << 16);
        }
    }
}

extern "C" void kernel_launch(void* const* d_in, const int* in_sizes, int n_in,
                              void* d_out, int out_size, void* d_ws, size_t ws_size,
                              hipStream_t stream)
{
    const float* x  = (const float*)d_in[0];
    const float* Wq = (const float*)d_in[1];
    const float* bq = (const float*)d_in[2];
    const float* Wk = (const float*)d_in[3];
    const float* bk = (const float*)d_in[4];
    const float* Wv = (const float*)d_in[5];
    const float* bv = (const float*)d_in[6];
    const float* Wo = (const float*)d_in[7];
    const float* bo = (const float*)d_in[8];
    float* out = (float*)d_out;

    const size_t NX = (size_t)MROWS * DIMN;   // 4 Mi elems
    const size_t NW = (size_t)DIMN * DIMN;    // 1 Mi elems

    u16* Xh  = (u16*)d_ws;
    u16* Xl  = Xh  + NX;
    u16* WhQ = Xl  + NX;
    u16* WlQ = WhQ + NW;
    u16* WhK = WlQ + NW;
    u16* WlK = WhK + NW;
    u16* WhV = WlK + NW;
    u16* WlV = WhV + NW;
    u16* WhO = WlV + NW;
    u16* WlO = WhO + NW;
    u16* Qh  = WlO + NW;
    u16* Ql  = Qh + NX;
    u16* Kh  = Ql + NX;
    u16* Kl  = Kh + NX;
    u16* Vth = Kl + NX;
    u16* Vtl = Vth + NX;
    float* Vw = (float*)(Vtl + NX);           // NX fp32
    u16* AH = Xh;                              // reuse (x-split dead after QKV gemm)
    u16* AL = Xl;
    // total: 16 + 16 + 32 + 16 + 16 = 96 MB

    const int n4x = (int)(NX / 4);
    const int n4w = (int)(NW / 4);
    split_hilo<<<n4x/256, 256, 0, stream>>>(x,  Xh,  Xl,  n4x);
    split_hilo<<<n4w/256, 256, 0, stream>>>(Wq, WhQ, WlQ, n4w);
    split_hilo<<<n4w/256, 256, 0, stream>>>(Wk, WhK, WlK, n4w);
    split_hilo<<<n4w/256, 256, 0, stream>>>(Wv, WhV, WlV, n4w);
    split_hilo<<<n4w/256, 256, 0, stream>>>(Wo, WhO, WlO, n4w);

    dim3 gq(DIMN / BN, MROWS / BM, 3);
    mfma_gemm<true><<<gq, 256, 0, stream>>>(Xh, Xl, WhQ, WlQ, WhK, WlK, WhV, WlV,
                                            bq, bk, bv, Qh, Ql, Kh, Kl, Vw, nullptr);

    dim3 gv(SEQ / 64, BATCH * NH);
    convV<<<gv, 256, 0, stream>>>(Vw, Vth, Vtl);

    dim3 ga(SEQ / 64, BATCH * NH);
    attn_mfma<<<ga, 256, 0, stream>>>(Qh, Ql, Kh, Kl, Vth, Vtl, AH, AL);

    dim3 gp(DIMN / BN, MROWS / BM, 1);
    mfma_gemm<false><<<gp, 256, 0, stream>>>(AH, AL, WhO, WlO, nullptr, nullptr,
                                             nullptr, nullptr, bo, nullptr, nullptr,
                                             nullptr, nullptr, nullptr, nullptr,
                                             nullptr, out);
}

// Round 4
// 380.194 us; speedup vs baseline: 1.2136x; 1.2136x over previous
//
#include <hip/hip_runtime.h>
#include <math.h>

#define DIMN 1024
#define NH 16
#define HD 64
#define BATCH 2
#define SEQ 2048
#define MROWS (BATCH*SEQ)   // 4096

typedef unsigned short u16;
typedef unsigned int u32;
typedef __attribute__((ext_vector_type(8))) short bf16x8;  // 8 bf16 = 4 VGPR
typedef __attribute__((ext_vector_type(4))) float f32x4;

__device__ __forceinline__ u16 f2bf(float f) {             // RNE float->bf16 (bits)
    unsigned u = __float_as_uint(f);
    u += 0x7FFF + ((u >> 16) & 1);
    return (u16)(u >> 16);
}
__device__ __forceinline__ float bf2f(u16 s) {
    return __uint_as_float(((unsigned)s) << 16);
}

#define GLOADLDS16(g, s)                                                     \
    __builtin_amdgcn_global_load_lds(                                        \
        (const __attribute__((address_space(1))) void*)(g),                  \
        (__attribute__((address_space(3))) void*)(s), 16, 0, 0)

// ---------------- hi/lo split: fp32 -> bf16 hi + bf16 lo ----------------
__global__ __launch_bounds__(256)
void split_hilo(const float* __restrict__ src, u16* __restrict__ h,
                u16* __restrict__ l, int n4)
{
    int i = blockIdx.x * 256 + threadIdx.x;
    if (i >= n4) return;
    float4 v = ((const float4*)src)[i];
    ushort4 hv, lv;
    hv.x = f2bf(v.x); lv.x = f2bf(v.x - bf2f(hv.x));
    hv.y = f2bf(v.y); lv.y = f2bf(v.y - bf2f(hv.y));
    hv.z = f2bf(v.z); lv.z = f2bf(v.z - bf2f(hv.z));
    hv.w = f2bf(v.w); lv.w = f2bf(v.w - bf2f(hv.w));
    ((ushort4*)h)[i] = hv;
    ((ushort4*)l)[i] = lv;
}

// ---------------- split-bf16 MFMA GEMM: Y = A @ W^T + bias ----------------
#define BM 128
#define BN 128
#define BK 32

template<bool QKV>
__global__ __launch_bounds__(256)
void mfma_gemm(const u16* __restrict__ Ah, const u16* __restrict__ Al,
               const u16* __restrict__ Wh0, const u16* __restrict__ Wl0,
               const u16* __restrict__ Wh1, const u16* __restrict__ Wl1,
               const u16* __restrict__ Wh2, const u16* __restrict__ Wl2,
               const float* __restrict__ b0, const float* __restrict__ b1,
               const float* __restrict__ b2,
               u16* __restrict__ Qh, u16* __restrict__ Ql,
               u16* __restrict__ Kh, u16* __restrict__ Kl,
               float* __restrict__ Vw, float* __restrict__ Yout)
{
    __shared__ u16 AhS[BM*BK], AlS[BM*BK], WhS[BN*BK], WlS[BN*BK];  // 32 KB

    const u16* Wh = Wh0; const u16* Wl = Wl0; const float* bias = b0;
    if (QKV) {
        if (blockIdx.z == 1)      { Wh = Wh1; Wl = Wl1; bias = b1; }
        else if (blockIdx.z == 2) { Wh = Wh2; Wl = Wl2; bias = b2; }
    }

    const int tid  = threadIdx.x;
    const int lane = tid & 63;
    const int wid  = tid >> 6;
    const int wr   = wid >> 1;
    const int wc   = wid & 1;

    const int m0 = blockIdx.y * BM;
    const int n0 = blockIdx.x * BN;

    const int srow = lane >> 2;
    const int skc  = (lane & 3) << 3;
    const int c0 = wid * 2, c1 = wid * 2 + 1;
    const size_t aoffg0 = (size_t)(m0 + c0*16 + srow) * DIMN + skc;
    const size_t aoffg1 = (size_t)(m0 + c1*16 + srow) * DIMN + skc;
    const size_t woffg0 = (size_t)(n0 + c0*16 + srow) * DIMN + skc;
    const size_t woffg1 = (size_t)(n0 + c1*16 + srow) * DIMN + skc;

    f32x4 acc[4][4];
    #pragma unroll
    for (int m = 0; m < 4; ++m)
        #pragma unroll
        for (int n = 0; n < 4; ++n)
            acc[m][n] = (f32x4){0.f, 0.f, 0.f, 0.f};

    const int fr = lane & 15;
    const int fq = lane >> 4;
    const int aoff = (wr*64 + fr) * BK + fq*8;
    const int boff = (wc*64 + fr) * BK + fq*8;

    for (int k0 = 0; k0 < DIMN; k0 += BK) {
        GLOADLDS16(Ah + aoffg0 + k0, &AhS[c0*512]);
        GLOADLDS16(Ah + aoffg1 + k0, &AhS[c1*512]);
        GLOADLDS16(Al + aoffg0 + k0, &AlS[c0*512]);
        GLOADLDS16(Al + aoffg1 + k0, &AlS[c1*512]);
        GLOADLDS16(Wh + woffg0 + k0, &WhS[c0*512]);
        GLOADLDS16(Wh + woffg1 + k0, &WhS[c1*512]);
        GLOADLDS16(Wl + woffg0 + k0, &WlS[c0*512]);
        GLOADLDS16(Wl + woffg1 + k0, &WlS[c1*512]);
        __syncthreads();

        bf16x8 ah[4], al[4], bh[4], bl[4];
        #pragma unroll
        for (int m = 0; m < 4; ++m) {
            ah[m] = *(const bf16x8*)&AhS[aoff + m*16*BK];
            al[m] = *(const bf16x8*)&AlS[aoff + m*16*BK];
        }
        #pragma unroll
        for (int n = 0; n < 4; ++n) {
            bh[n] = *(const bf16x8*)&WhS[boff + n*16*BK];
            bl[n] = *(const bf16x8*)&WlS[boff + n*16*BK];
        }
        #pragma unroll
        for (int m = 0; m < 4; ++m)
            #pragma unroll
            for (int n = 0; n < 4; ++n) {
                acc[m][n] = __builtin_amdgcn_mfma_f32_16x16x32_bf16(ah[m], bh[n], acc[m][n], 0, 0, 0);
                acc[m][n] = __builtin_amdgcn_mfma_f32_16x16x32_bf16(ah[m], bl[n], acc[m][n], 0, 0, 0);
                acc[m][n] = __builtin_amdgcn_mfma_f32_16x16x32_bf16(al[m], bh[n], acc[m][n], 0, 0, 0);
            }
        __syncthreads();
    }

    // C/D map: col = lane&15, row = (lane>>4)*4 + j   [m89-verified]
    #pragma unroll
    for (int n = 0; n < 4; ++n) {
        const int col = n0 + wc*64 + n*16 + fr;
        const float bv = bias[col];
        #pragma unroll
        for (int m = 0; m < 4; ++m) {
            #pragma unroll
            for (int j = 0; j < 4; ++j) {
                const int row = m0 + wr*64 + m*16 + fq*4 + j;
                float v = acc[m][n][j] + bv;
                if (QKV) {
                    const int b_ = row >> 11, t = row & (SEQ - 1);
                    const int hh = col >> 6, d = col & 63;
                    const size_t rb = (((size_t)b_*NH + hh)*SEQ + t)*HD;
                    if (blockIdx.z == 0) {            // Q: scaled, plain
                        v *= 0.03125f;
                        u16 hv = f2bf(v), lv = f2bf(v - bf2f(hv));
                        Qh[rb + d] = hv; Ql[rb + d] = lv;
                    } else if (blockIdx.z == 1) {     // K: swizzled
                        u16 hv = f2bf(v), lv = f2bf(v - bf2f(hv));
                        const int ds = d ^ ((t & 7) << 3);
                        Kh[rb + ds] = hv; Kl[rb + ds] = lv;
                    } else {                          // V: fp32 plain
                        Vw[rb + d] = v;
                    }
                } else {
                    Yout[(size_t)row*DIMN + col] = v;
                }
            }
        }
    }
}

// ---- V transpose + hi/lo + kc-slot swizzle: [B,H,T,64] -> [B,H,64,T] bf16 ----
// Within each 32-t granule, 16B slot s -> s ^ (d&3)  (kills the 4-way LDS
// conflict on the attention V reads; staging copies granules verbatim).
__global__ __launch_bounds__(256)
void convV(const float* __restrict__ Vw, u16* __restrict__ Vth, u16* __restrict__ Vtl)
{
    __shared__ float Vs[64][68];
    const int tid = threadIdx.x;
    const int bh = blockIdx.y;
    const int t0 = blockIdx.x * 64;
    const float* src = Vw + ((size_t)bh*SEQ + t0)*HD;
    #pragma unroll
    for (int k = 0; k < 4; ++k) {
        int f4 = tid + k*256;
        int r = f4 >> 4, c4 = (f4 & 15) << 2;
        *(float4*)&Vs[r][c4] = *(const float4*)(src + (size_t)r*HD + c4);
    }
    __syncthreads();
    const int d  = tid >> 2;            // 0..63
    const int q2 = (tid & 3) << 4;      // base t: 0,16,32,48
    u16* oh = Vth + ((size_t)bh*HD + d)*SEQ + t0;
    u16* ol = Vtl + ((size_t)bh*HD + d)*SEQ + t0;
    #pragma unroll
    for (int p = 0; p < 4; ++p) {
        const int lt = q2 + p*4;                      // linear t, run of 4
        const int t_sw = (lt & 32) | ((((lt >> 3) & 3) ^ (d & 3)) << 3) | (lt & 7);
        ushort4 hv, lv; float v;
        v = Vs[lt + 0][d]; hv.x = f2bf(v); lv.x = f2bf(v - bf2f(hv.x));
        v = Vs[lt + 1][d]; hv.y = f2bf(v); lv.y = f2bf(v - bf2f(hv.y));
        v = Vs[lt + 2][d]; hv.z = f2bf(v); lv.z = f2bf(v - bf2f(hv.z));
        v = Vs[lt + 3][d]; hv.w = f2bf(v); lv.w = f2bf(v - bf2f(hv.w));
        *(ushort4*)(oh + t_sw) = hv;
        *(ushort4*)(ol + t_sw) = lv;
    }
}

// ---------------- MFMA flash attention ----------------
// Pair-balanced: block x handles q-tiles {x, 31-x} sequentially -> every
// block does exactly 68 k-tile iterations (uniform). Grid (16, B*NH) = 512.
// Swapped QK^T (S^T = mfma(K,Q)): in-register softmax, q = lane&15.
// PV: O^T = mfma(Vt, P); P via per-wave LDS (stride 40 u16: conflict-free).
// K global-pre-swizzled, Vt slot-swizzled: staged linear, read swizzled.
__global__ __launch_bounds__(256)
void attn_mfma(const u16* __restrict__ Qhg, const u16* __restrict__ Qlg,
               const u16* __restrict__ Khg, const u16* __restrict__ Klg,
               const u16* __restrict__ Vthg, const u16* __restrict__ Vtlg,
               u16* __restrict__ AH, u16* __restrict__ AL)
{
    __shared__ u16 KVS[2][4][2048];   // [buf][Kh,Kl,Vth,Vtl][tile] 32 KB
    __shared__ u16 PhS[4][640];       // per-wave P hi [16q][stride 40] 5 KB
    __shared__ u16 PlS[4][640];

    const int tid  = threadIdx.x;
    const int lane = tid & 63;
    const int w    = tid >> 6;
    const int fr   = lane & 15;
    const int fq   = lane >> 4;
    const int bh   = blockIdx.y;
    const int b_   = bh >> 4;
    const int h    = bh & 15;

    auto stage = [&](int buf, int kt2) {
        u16* dst = &KVS[buf][w][0];
        if (w < 2) {
            const u16* g = (w == 0 ? Khg : Klg) +
                ((size_t)bh*SEQ + (size_t)kt2*32 + (lane>>3))*HD + ((lane&7)<<3);
            #pragma unroll
            for (int i = 0; i < 4; ++i)
                GLOADLDS16(g + (size_t)i*8*HD, dst + i*512);
        } else {
            const u16* g = (w == 2 ? Vthg : Vtlg) +
                ((size_t)bh*HD + (lane>>2))*SEQ + (size_t)kt2*32 + ((lane&3)<<3);
            #pragma unroll
            for (int i = 0; i < 4; ++i)
                GLOADLDS16(g + (size_t)i*16*SEQ, dst + i*512);
        }
    };

    #pragma unroll 1
    for (int pass = 0; pass < 2; ++pass) {
        const int qt   = pass ? (31 - blockIdx.x) : blockIdx.x;
        const int qabs = qt*64 + w*16 + fr;
        const int nt   = 2*qt + 2;

        // Q fragments (B-operand): tile-invariant, straight from global.
        bf16x8 qh[2], ql[2];
        {
            const size_t qrow = ((size_t)bh*SEQ + qabs)*HD;
            #pragma unroll
            for (int ks = 0; ks < 2; ++ks) {
                qh[ks] = *(const bf16x8*)&Qhg[qrow + ks*32 + (fq<<3)];
                ql[ks] = *(const bf16x8*)&Qlg[qrow + ks*32 + (fq<<3)];
            }
        }

        f32x4 o[4];
        #pragma unroll
        for (int md = 0; md < 4; ++md) o[md] = (f32x4){0.f,0.f,0.f,0.f};
        float mrun = -INFINITY, lrun = 0.f;

        __syncthreads();               // prior pass's LDS reads complete
        stage(0, 0);
        int cur = 0;

        for (int kt = 0; kt < nt; ++kt) {
            __syncthreads();                       // staged tile landed
            if (kt + 1 < nt) stage(cur ^ 1, kt + 1);

            // ---- QK^T (S^T): A = K tile rows kc, B = Q frags ----
            f32x4 s0 = (f32x4){0.f,0.f,0.f,0.f};
            f32x4 s1 = (f32x4){0.f,0.f,0.f,0.f};
            #pragma unroll
            for (int ks = 0; ks < 2; ++ks) {
                const int sl = (((ks*4 + fq) ^ (fr & 7)) << 3);   // swizzled d-slot
                bf16x8 a0h = *(const bf16x8*)&KVS[cur][0][fr*64 + sl];
                bf16x8 a0l = *(const bf16x8*)&KVS[cur][1][fr*64 + sl];
                bf16x8 a1h = *(const bf16x8*)&KVS[cur][0][(16+fr)*64 + sl];
                bf16x8 a1l = *(const bf16x8*)&KVS[cur][1][(16+fr)*64 + sl];
                s0 = __builtin_amdgcn_mfma_f32_16x16x32_bf16(a0h, qh[ks], s0, 0,0,0);
                s0 = __builtin_amdgcn_mfma_f32_16x16x32_bf16(a0h, ql[ks], s0, 0,0,0);
                s0 = __builtin_amdgcn_mfma_f32_16x16x32_bf16(a0l, qh[ks], s0, 0,0,0);
                s1 = __builtin_amdgcn_mfma_f32_16x16x32_bf16(a1h, qh[ks], s1, 0,0,0);
                s1 = __builtin_amdgcn_mfma_f32_16x16x32_bf16(a1h, ql[ks], s1, 0,0,0);
                s1 = __builtin_amdgcn_mfma_f32_16x16x32_bf16(a1l, qh[ks], s1, 0,0,0);
            }

            const int kb = kt*32 + fq*4;
            #pragma unroll
            for (int j = 0; j < 4; ++j) {
                if (kb + j      > qabs) s0[j] = -INFINITY;
                if (kb + 16 + j > qabs) s1[j] = -INFINITY;
            }

            // ---- online softmax (row q = fr, spread over fq lanes) ----
            float pm = fmaxf(fmaxf(fmaxf(s0[0],s0[1]), fmaxf(s0[2],s0[3])),
                             fmaxf(fmaxf(s1[0],s1[1]), fmaxf(s1[2],s1[3])));
            pm = fmaxf(pm, __shfl_xor(pm, 16));
            pm = fmaxf(pm, __shfl_xor(pm, 32));
            const float mnew = fmaxf(mrun, pm);
            const float fac  = __expf(mrun - mnew);
            float p[8];
            #pragma unroll
            for (int j = 0; j < 4; ++j) {
                p[j]   = __expf(s0[j] - mnew);
                p[4+j] = __expf(s1[j] - mnew);
            }
            float ls = ((p[0]+p[1]) + (p[2]+p[3])) + ((p[4]+p[5]) + (p[6]+p[7]));
            ls += __shfl_xor(ls, 16);
            ls += __shfl_xor(ls, 32);
            lrun = lrun * fac + ls;
            mrun = mnew;
            #pragma unroll
            for (int md = 0; md < 4; ++md) {
                o[md][0] *= fac; o[md][1] *= fac; o[md][2] *= fac; o[md][3] *= fac;
            }

            // ---- P -> bf16 hi/lo -> per-wave LDS [16q][40-stride] ----
            u16 ph[8], pl[8];
            #pragma unroll
            for (int i = 0; i < 8; ++i) {
                ph[i] = f2bf(p[i]);
                pl[i] = f2bf(p[i] - bf2f(ph[i]));
            }
            {
                const int pb = fr*40 + fq*4;
                uint2 w0, w1;
                w0.x = (u32)ph[0] | ((u32)ph[1] << 16);
                w0.y = (u32)ph[2] | ((u32)ph[3] << 16);
                w1.x = (u32)ph[4] | ((u32)ph[5] << 16);
                w1.y = (u32)ph[6] | ((u32)ph[7] << 16);
                *(uint2*)&PhS[w][pb]      = w0;
                *(uint2*)&PhS[w][pb + 16] = w1;
                w0.x = (u32)pl[0] | ((u32)pl[1] << 16);
                w0.y = (u32)pl[2] | ((u32)pl[3] << 16);
                w1.x = (u32)pl[4] | ((u32)pl[5] << 16);
                w1.y = (u32)pl[6] | ((u32)pl[7] << 16);
                *(uint2*)&PlS[w][pb]      = w0;
                *(uint2*)&PlS[w][pb + 16] = w1;
            }

            // ---- PV (O^T): A = Vt tile (rows d, slot-swizzled), B = P ----
            bf16x8 bph = *(const bf16x8*)&PhS[w][fr*40 + (fq<<3)];
            bf16x8 bpl = *(const bf16x8*)&PlS[w][fr*40 + (fq<<3)];
            #pragma unroll
            for (int md = 0; md < 4; ++md) {
                const int vsl = ((fq ^ (fr & 3)) << 3);
                bf16x8 avh = *(const bf16x8*)&KVS[cur][2][(md*16+fr)*32 + vsl];
                bf16x8 avl = *(const bf16x8*)&KVS[cur][3][(md*16+fr)*32 + vsl];
                o[md] = __builtin_amdgcn_mfma_f32_16x16x32_bf16(avh, bph, o[md], 0,0,0);
                o[md] = __builtin_amdgcn_mfma_f32_16x16x32_bf16(avh, bpl, o[md], 0,0,0);
                o[md] = __builtin_amdgcn_mfma_f32_16x16x32_bf16(avl, bph, o[md], 0,0,0);
            }
            cur ^= 1;
        }

        // ---- epilogue: lane holds q=qabs, d = md*16 + fq*4 + j ----
        const float inv = 1.f / lrun;
        const size_t ob = ((size_t)b_*SEQ + qabs)*DIMN + h*64;
        #pragma unroll
        for (int md = 0; md < 4; ++md) {
            #pragma unroll
            for (int pr = 0; pr < 2; ++pr) {
                const int d0 = md*16 + fq*4 + pr*2;
                const float v0 = o[md][pr*2]   * inv;
                const float v1 = o[md][pr*2+1] * inv;
                u16 h0 = f2bf(v0), l0 = f2bf(v0 - bf2f(h0));
                u16 h1 = f2bf(v1), l1 = f2bf(v1 - bf2f(h1));
                *(u32*)&AH[ob + d0] = (u32)h0 | ((u32)h1 << 16);
                *(u32*)&AL[ob + d0] = (u32)l0 | ((u32)l1 << 16);
            }
        }
    }
}

extern "C" void kernel_launch(void* const* d_in, const int* in_sizes, int n_in,
                              void* d_out, int out_size, void* d_ws, size_t ws_size,
                              hipStream_t stream)
{
    const float* x  = (const float*)d_in[0];
    const float* Wq = (const float*)d_in[1];
    const float* bq = (const float*)d_in[2];
    const float* Wk = (const float*)d_in[3];
    const float* bk = (const float*)d_in[4];
    const float* Wv = (const float*)d_in[5];
    const float* bv = (const float*)d_in[6];
    const float* Wo = (const float*)d_in[7];
    const float* bo = (const float*)d_in[8];
    float* out = (float*)d_out;

    const size_t NX = (size_t)MROWS * DIMN;   // 4 Mi elems
    const size_t NW = (size_t)DIMN * DIMN;    // 1 Mi elems

    u16* Xh  = (u16*)d_ws;
    u16* Xl  = Xh  + NX;
    u16* WhQ = Xl  + NX;
    u16* WlQ = WhQ + NW;
    u16* WhK = WlQ + NW;
    u16* WlK = WhK + NW;
    u16* WhV = WlK + NW;
    u16* WlV = WhV + NW;
    u16* WhO = WlV + NW;
    u16* WlO = WhO + NW;
    u16* Qh  = WlO + NW;
    u16* Ql  = Qh + NX;
    u16* Kh  = Ql + NX;
    u16* Kl  = Kh + NX;
    u16* Vth = Kl + NX;
    u16* Vtl = Vth + NX;
    float* Vw = (float*)(Vtl + NX);           // NX fp32
    u16* AH = Xh;                              // reuse (x-split dead after QKV gemm)
    u16* AL = Xl;

    const int n4x = (int)(NX / 4);
    const int n4w = (int)(NW / 4);
    split_hilo<<<n4x/256, 256, 0, stream>>>(x,  Xh,  Xl,  n4x);
    split_hilo<<<n4w/256, 256, 0, stream>>>(Wq, WhQ, WlQ, n4w);
    split_hilo<<<n4w/256, 256, 0, stream>>>(Wk, WhK, WlK, n4w);
    split_hilo<<<n4w/256, 256, 0, stream>>>(Wv, WhV, WlV, n4w);
    split_hilo<<<n4w/256, 256, 0, stream>>>(Wo, WhO, WlO, n4w);

    dim3 gq(DIMN / BN, MROWS / BM, 3);
    mfma_gemm<true><<<gq, 256, 0, stream>>>(Xh, Xl, WhQ, WlQ, WhK, WlK, WhV, WlV,
                                            bq, bk, bv, Qh, Ql, Kh, Kl, Vw, nullptr);

    dim3 gv(SEQ / 64, BATCH * NH);
    convV<<<gv, 256, 0, stream>>>(Vw, Vth, Vtl);

    dim3 ga(16, BATCH * NH);                  // pair-balanced: 68 tiles/block
    attn_mfma<<<ga, 256, 0, stream>>>(Qh, Ql, Kh, Kl, Vth, Vtl, AH, AL);

    dim3 gp(DIMN / BN, MROWS / BM, 1);
    mfma_gemm<false><<<gp, 256, 0, stream>>>(AH, AL, WhO, WlO, nullptr, nullptr,
                                             nullptr, nullptr, bo, nullptr, nullptr,
                                             nullptr, nullptr, nullptr, nullptr,
                                             nullptr, out);
}